// Round 1
// baseline (471.544 us; speedup 1.0000x reference)
//
#include <hip/hip_runtime.h>

#define Bn 4
#define Cn 32
#define Hn 720
#define Wn 720
#define W4 (Wn / 4)            // 180
#define HW (Hn * Wn)
#define NPIX (Bn * Hn * Wn)    // 2,073,600
#define NV (NPIX / 4)          // 518,400 float4 elements

// K0: wsum[o*3+kh] = sum_i conv_w[o,i,kh,0]
__global__ void wsum_kernel(const float* __restrict__ conv_w,
                            float* __restrict__ wsum) {
    int t = threadIdx.x;
    if (t < 96) {
        int o = t / 3, kh = t - o * 3;
        float acc = 0.f;
        #pragma unroll
        for (int i = 0; i < Cn; ++i)
            acc += conv_w[(o * Cn + i) * 3 + kh];
        wsum[t] = acc;
    }
}

// K1: s[b,h,w] = sum_c x[b,c,h,w]   (float4-vectorized over w)
__global__ void csum_kernel(const float* __restrict__ x,
                            float* __restrict__ s) {
    int idx = blockIdx.x * blockDim.x + threadIdx.x;
    if (idx >= NV) return;
    int b = idx / (Hn * W4);
    int rem = idx - b * (Hn * W4);
    const float4* xp = (const float4*)x + (size_t)b * Cn * Hn * W4 + rem;
    float4 acc = make_float4(0.f, 0.f, 0.f, 0.f);
    #pragma unroll 8
    for (int c = 0; c < Cn; ++c) {
        float4 v = xp[(size_t)c * Hn * W4];
        acc.x += v.x; acc.y += v.y; acc.z += v.z; acc.w += v.w;
    }
    ((float4*)s)[idx] = acc;
}

// K2: d[b,h,w] = (1/9) * sum_{t=-4..4} s[b,h+t,w+t]  (zero outside)
__global__ void diag_kernel(const float* __restrict__ s,
                            float* __restrict__ d) {
    int idx = blockIdx.x * blockDim.x + threadIdx.x;
    if (idx >= NV) return;
    int b = idx / (Hn * W4);
    int rem = idx - b * (Hn * W4);
    int h = rem / W4;
    int w0 = (rem - h * W4) * 4;
    const float* sb = s + (size_t)b * HW;
    float acc0 = 0.f, acc1 = 0.f, acc2 = 0.f, acc3 = 0.f;
    #pragma unroll
    for (int t = -4; t <= 4; ++t) {
        int hh = h + t;
        if (hh < 0 || hh >= Hn) continue;
        const float* row = sb + (size_t)hh * Wn;
        int ww = w0 + t;
        if (ww >= 0 && ww < Wn)         acc0 += row[ww];
        if (ww + 1 >= 0 && ww + 1 < Wn) acc1 += row[ww + 1];
        if (ww + 2 >= 0 && ww + 2 < Wn) acc2 += row[ww + 2];
        if (ww + 3 >= 0 && ww + 3 < Wn) acc3 += row[ww + 3];
    }
    const float inv9 = 1.f / 9.f;
    ((float4*)d)[idx] = make_float4(acc0 * inv9, acc1 * inv9,
                                    acc2 * inv9, acc3 * inv9);
}

// K3: out[b,o,h,w] = sum_{kh=0..2} wsum[o,kh] * d[b,h+kh-1,w]
__global__ void conv_kernel(const float* __restrict__ d,
                            const float* __restrict__ wsum,
                            float* __restrict__ out) {
    __shared__ float ws[96];
    if (threadIdx.x < 96) ws[threadIdx.x] = wsum[threadIdx.x];
    __syncthreads();
    int idx = blockIdx.x * blockDim.x + threadIdx.x;
    if (idx >= NV) return;
    int b = idx / (Hn * W4);
    int rem = idx - b * (Hn * W4);
    int h = rem / W4;
    int w4 = rem - h * W4;
    const float4* db = (const float4*)d + (size_t)b * Hn * W4;
    float4 z = make_float4(0.f, 0.f, 0.f, 0.f);
    float4 dm = (h > 0)      ? db[(size_t)(h - 1) * W4 + w4] : z;
    float4 dc =                db[(size_t)h * W4 + w4];
    float4 dp = (h < Hn - 1) ? db[(size_t)(h + 1) * W4 + w4] : z;
    float4* ob = (float4*)out + (size_t)b * Cn * Hn * W4 + (size_t)h * W4 + w4;
    #pragma unroll
    for (int o = 0; o < Cn; ++o) {
        float k0 = ws[o * 3 + 0], k1 = ws[o * 3 + 1], k2 = ws[o * 3 + 2];
        float4 r;
        r.x = k0 * dm.x + k1 * dc.x + k2 * dp.x;
        r.y = k0 * dm.y + k1 * dc.y + k2 * dp.y;
        r.z = k0 * dm.z + k1 * dc.z + k2 * dp.z;
        r.w = k0 * dm.w + k1 * dc.w + k2 * dp.w;
        ob[(size_t)o * Hn * W4] = r;
    }
}

extern "C" void kernel_launch(void* const* d_in, const int* in_sizes, int n_in,
                              void* d_out, int out_size, void* d_ws, size_t ws_size,
                              hipStream_t stream) {
    const float* x = (const float*)d_in[0];
    const float* conv_w = (const float*)d_in[1];
    float* out = (float*)d_out;

    float* s    = (float*)d_ws;                 // NPIX floats (8.3 MB)
    float* dbuf = s + NPIX;                     // NPIX floats (8.3 MB)
    float* wsum = dbuf + NPIX;                  // 96 floats

    wsum_kernel<<<1, 96, 0, stream>>>(conv_w, wsum);

    const int threads = 256;
    const int blocks = (NV + threads - 1) / threads;  // 2025
    csum_kernel<<<blocks, threads, 0, stream>>>(x, s);
    diag_kernel<<<blocks, threads, 0, stream>>>(s, dbuf);
    conv_kernel<<<blocks, threads, 0, stream>>>(dbuf, wsum, out);
}

// Round 2
// 423.416 us; speedup vs baseline: 1.1137x; 1.1137x over previous
//
#include <hip/hip_runtime.h>

#define Bn 4
#define Cn 32
#define Hn 720
#define Wn 720
#define W4 (Wn / 4)              // 180
#define NV (Bn * Hn * W4)        // 518,400 float4-threads

// zero-padded channel-sum buffer: 5-row halo top/bottom, 4-col halo left/right
#define PH (Hn + 10)             // 730
#define PW (Wn + 8)              // 728
#define SPAD_ELEMS (Bn * PH * PW)

typedef float v4 __attribute__((ext_vector_type(4)));

// K0: wsum[o*3+kh] = sum_i conv_w[o,i,kh,0]
__global__ void wsum_kernel(const float* __restrict__ conv_w,
                            float* __restrict__ wsum) {
    int t = threadIdx.x;
    if (t < 96) {
        int o = t / 3, kh = t - o * 3;
        float acc = 0.f;
        #pragma unroll
        for (int i = 0; i < Cn; ++i)
            acc += conv_w[(o * Cn + i) * 3 + kh];
        wsum[t] = acc;
    }
}

// K1: sp[b, 5+h, 4+w] = sum_c x[b,c,h,w]   (padded layout, halo pre-zeroed)
__global__ void csum_kernel(const float* __restrict__ x,
                            float* __restrict__ sp) {
    int idx = blockIdx.x * blockDim.x + threadIdx.x;
    if (idx >= NV) return;
    int b = idx / (Hn * W4);
    int rem = idx - b * (Hn * W4);
    int h = rem / W4;
    int w4 = rem - h * W4;
    const v4* xp = (const v4*)x + (size_t)b * Cn * Hn * W4 + rem;
    v4 acc = {0.f, 0.f, 0.f, 0.f};
    #pragma unroll 8
    for (int c = 0; c < Cn; ++c) {
        v4 v = __builtin_nontemporal_load(&xp[(size_t)c * Hn * W4]);
        acc += v;
    }
    v4* dst = (v4*)(sp + ((size_t)b * PH + 5 + h) * PW + 4) + w4;
    *dst = acc;
}

// K2: fused diag-pool + 3x1 conv.
// d[r] = (1/9) * sum_{t=-4..4} s[r+t, w+t];  out[o,h] = sum_j ws[o,j]*d[h-1+j]
__global__ void fused_kernel(const float* __restrict__ sp,
                             const float* __restrict__ wsum,
                             float* __restrict__ out) {
    __shared__ float ws[96];
    if (threadIdx.x < 96) ws[threadIdx.x] = wsum[threadIdx.x];
    __syncthreads();
    int idx = blockIdx.x * blockDim.x + threadIdx.x;
    if (idx >= NV) return;
    int b = idx / (Hn * W4);
    int rem = idx - b * (Hn * W4);
    int h = rem / W4;
    int w4 = rem - h * W4;
    // center pointer at padded (row 5+h, col 4 + 4*w4)
    const float* srow = sp + ((size_t)b * PH + 5 + h) * PW + 4 + 4 * w4;

    float a0[4] = {0,0,0,0}, a1[4] = {0,0,0,0}, a2[4] = {0,0,0,0};
    #pragma unroll
    for (int r = -5; r <= 5; ++r) {
        const float* p = srow + (long)r * PW - 4;   // padded col (w0-4), 16B aligned
        v4 u0 = *(const v4*)p;
        v4 u1 = *(const v4*)(p + 4);
        v4 u2 = *(const v4*)(p + 8);
        float v[12] = {u0[0],u0[1],u0[2],u0[3],
                       u1[0],u1[1],u1[2],u1[3],
                       u2[0],u2[1],u2[2],u2[3]};
        #pragma unroll
        for (int j = 0; j < 3; ++j) {
            const int t = r + 1 - j;                // tap index for d-row h-1+j
            if (t >= -4 && t <= 4) {
                float* a = (j == 0) ? a0 : (j == 1) ? a1 : a2;
                #pragma unroll
                for (int l = 0; l < 4; ++l) a[l] += v[4 + l + t];
            }
        }
    }
    // conv zero-padding in h: d[-1] and d[720] are exactly zero
    if (h == 0) { a0[0]=a0[1]=a0[2]=a0[3]=0.f; }
    if (h == Hn - 1) { a2[0]=a2[1]=a2[2]=a2[3]=0.f; }

    const float inv9 = 1.f / 9.f;
    float* ob = out + (size_t)b * Cn * Hn * Wn + (size_t)h * Wn + 4 * w4;
    #pragma unroll
    for (int o = 0; o < Cn; ++o) {
        float k0 = ws[3*o] * inv9, k1 = ws[3*o+1] * inv9, k2 = ws[3*o+2] * inv9;
        v4 r;
        #pragma unroll
        for (int l = 0; l < 4; ++l)
            r[l] = k0 * a0[l] + k1 * a1[l] + k2 * a2[l];
        __builtin_nontemporal_store(r, (v4*)(ob + (size_t)o * Hn * Wn));
    }
}

extern "C" void kernel_launch(void* const* d_in, const int* in_sizes, int n_in,
                              void* d_out, int out_size, void* d_ws, size_t ws_size,
                              hipStream_t stream) {
    const float* x = (const float*)d_in[0];
    const float* conv_w = (const float*)d_in[1];
    float* out = (float*)d_out;

    float* sp   = (float*)d_ws;            // SPAD_ELEMS floats (~8.5 MB)
    float* wsum = sp + SPAD_ELEMS;         // 96 floats

    // zero the padded s buffer (halo must be 0; ws is poisoned 0xAA each call)
    hipMemsetAsync(sp, 0, (size_t)SPAD_ELEMS * sizeof(float), stream);

    wsum_kernel<<<1, 96, 0, stream>>>(conv_w, wsum);

    const int threads = 256;
    const int blocks = (NV + threads - 1) / threads;  // 2025
    csum_kernel<<<blocks, threads, 0, stream>>>(x, sp);
    fused_kernel<<<blocks, threads, 0, stream>>>(sp, wsum, out);
}